// Round 4
// baseline (626.889 us; speedup 1.0000x reference)
//
#include <hip/hip_runtime.h>
#include <hip/hip_bf16.h>
#include <math.h>

#define NNODES 100000
#define NSUB 16  // atomic-striping factor: 16x fewer same-line RMWs at the coherence point

// ---------------------------------------------------------------- utilities
__device__ __forceinline__ int edge_val(const void* eidx, int is64, size_t i) {
  if (is64) return (int)((const long long*)eidx)[i];
  return ((const int*)eidx)[i];
}

// Detect whether edge_index buffer is int64 or int32.
__global__ void k_detect(const void* eidx, int* flag) {
  int t = threadIdx.x;  // 64 threads, one wave
  int bad = 0;
  const unsigned long long* p = (const unsigned long long*)eidx;
  for (int i = t; i < 1024; i += 64)
    if (p[i] >> 32) bad = 1;
  unsigned long long b = __ballot(bad);
  if (t == 0) flag[0] = (b == 0ULL) ? 1 : 0;
}

// ---------------------------------------------------------------- degree (striped)
__global__ void k_count(const void* eidx, const int* __restrict__ flag,
                        int* __restrict__ cnt16, int E) {
  int e = blockIdx.x * blockDim.x + threadIdx.x;
  if (e >= E) return;
  int is64 = flag[0];
  int d = edge_val(eidx, is64, (size_t)E + e);
  atomicAdd(&cnt16[(size_t)(e & (NSUB - 1)) * NNODES + d], 1);
}

// sum the 16 stripes -> tot, dis
__global__ void k_dis(const int* __restrict__ cnt16, int* __restrict__ tot,
                      float* __restrict__ dis, int n) {
  int i = blockIdx.x * blockDim.x + threadIdx.x;
  if (i >= n) return;
  int t = 0;
  #pragma unroll
  for (int s = 0; s < NSUB; ++s) t += cnt16[(size_t)s * NNODES + i];
  tot[i] = t;
  dis[i] = rsqrtf((float)(t + 1));  // +1 = self loop
}

// ---------------------------------------------------------------- scan (3 kernels)
__global__ void k_scan_reduce(const int* __restrict__ tot, int* __restrict__ bsum, int n) {
  int idx = blockIdx.x * 256 + threadIdx.x;
  int v = (idx < n) ? tot[idx] : 0;
  #pragma unroll
  for (int d = 32; d > 0; d >>= 1) v += __shfl_down(v, d);
  __shared__ int ws4[4];
  if ((threadIdx.x & 63) == 0) ws4[threadIdx.x >> 6] = v;
  __syncthreads();
  if (threadIdx.x == 0) bsum[blockIdx.x] = ws4[0] + ws4[1] + ws4[2] + ws4[3];
}

// single block: inclusive scan of nb block sums -> exclusive in-place; total -> rowptr[n]
__global__ void k_scan_partials(int* bsum, int nb, int* rowptr, int n) {
  __shared__ int s[512];
  int t = threadIdx.x;  // 512 threads, nb <= 512
  int v = (t < nb) ? bsum[t] : 0;
  s[t] = v;
  __syncthreads();
  for (int d = 1; d < 512; d <<= 1) {
    int u = (t >= d) ? s[t - d] : 0;
    __syncthreads();
    s[t] += u;
    __syncthreads();
  }
  if (t < nb) bsum[t] = (t == 0) ? 0 : s[t - 1];
  if (t == 0) rowptr[n] = s[nb - 1];
}

// per-node exclusive prefix -> rowptr; also lay out the 16 per-node sub-segments
// cursor16[s][node] = rowptr[node] + sum_{s'<s} cnt16[s'][node]
__global__ void k_scan_final(const int* __restrict__ tot, const int* __restrict__ cnt16,
                             const int* __restrict__ bsum_ex, int* __restrict__ rowptr,
                             int* __restrict__ cursor16, int n) {
  __shared__ int s[256];
  int t = threadIdx.x;
  int idx = blockIdx.x * 256 + t;
  int v = (idx < n) ? tot[idx] : 0;
  s[t] = v;
  __syncthreads();
  for (int d = 1; d < 256; d <<= 1) {
    int u = (t >= d) ? s[t - d] : 0;
    __syncthreads();
    s[t] += u;
    __syncthreads();
  }
  if (idx < n) {
    int excl = bsum_ex[blockIdx.x] + s[t] - v;
    rowptr[idx] = excl;
    int run = excl;
    #pragma unroll
    for (int sb = 0; sb < NSUB; ++sb) {
      cursor16[(size_t)sb * NNODES + idx] = run;
      run += cnt16[(size_t)sb * NNODES + idx];
    }
  }
}

// ---------------------------------------------------------------- CSR scatter (striped)
__global__ void k_scatter(const void* eidx, const int* __restrict__ flag,
                          int* __restrict__ cursor16, int* __restrict__ col, int E) {
  int e = blockIdx.x * blockDim.x + threadIdx.x;
  if (e >= E) return;
  int is64 = flag[0];
  int s = edge_val(eidx, is64, e);
  int d = edge_val(eidx, is64, (size_t)E + e);
  int pos = atomicAdd(&cursor16[(size_t)(e & (NSUB - 1)) * NNODES + d], 1);
  col[pos] = s;
}

// ---------------------------------------------------------------- GEMM (N=16)
// thread-per-row; W reads are wave-uniform -> scalar loads; epilogue scales by dis[row]
template <int K>
__global__ void k_gemm(const float* __restrict__ x, const float* __restrict__ W,
                       const float* __restrict__ dis, float* __restrict__ out, int nrows) {
  int row = blockIdx.x * blockDim.x + threadIdx.x;
  if (row >= nrows) return;
  const float4* xr = (const float4*)(x + (size_t)row * K);
  float acc[16];
  #pragma unroll
  for (int j = 0; j < 16; ++j) acc[j] = 0.f;
  #pragma unroll 2
  for (int k4 = 0; k4 < K / 4; ++k4) {
    float4 xv = xr[k4];
    const float* xs = (const float*)&xv;
    #pragma unroll
    for (int kk = 0; kk < 4; ++kk) {
      #pragma unroll
      for (int j = 0; j < 16; ++j)
        acc[j] = fmaf(xs[kk], W[(size_t)(k4 * 4 + kk) * 16 + j], acc[j]);
    }
  }
  float dd = dis[row];
  float4* o = (float4*)(out + (size_t)row * 16);
  #pragma unroll
  for (int q = 0; q < 4; ++q)
    o[q] = make_float4(acc[q * 4] * dd, acc[q * 4 + 1] * dd,
                       acc[q * 4 + 2] * dd, acc[q * 4 + 3] * dd);
}

// ---------------------------------------------------------------- aggregation
// wave per node; lane = (edge_slot 0..3, j 0..15)
// g = dis*h pre-scaled; out_j = act( dis[node]*(sum_e g[col[e]][j] + g[node][j]) + b[j] )
template <int MODE>
__global__ void k_agg(const float* __restrict__ g, const int* __restrict__ col,
                      const int* __restrict__ rowptr, const float* __restrict__ dis,
                      const float* __restrict__ bias, float* __restrict__ out) {
  int wid = threadIdx.x >> 6;
  int node = blockIdx.x * (blockDim.x >> 6) + wid;
  if (node >= NNODES) return;
  int lane = threadIdx.x & 63;
  int slot = lane >> 4;
  int j = lane & 15;
  int beg = rowptr[node], end = rowptr[node + 1];
  float acc = 0.f;
  for (int e = beg + slot; e < end; e += 4) {
    int s = col[e];
    acc += g[(size_t)s * 16 + j];
  }
  acc += __shfl_xor(acc, 16);
  acc += __shfl_xor(acc, 32);
  float z = dis[node] * (acc + g[(size_t)node * 16 + j]) + bias[j];
  if (MODE == 0) {
    z = fmaxf(z, 0.f);
    if (lane < 16) out[(size_t)node * 16 + j] = z;
  } else {
    float m = z;
    #pragma unroll
    for (int d = 1; d < 16; d <<= 1) m = fmaxf(m, __shfl_xor(m, d));
    float ex = expf(z - m);
    float sum = ex;
    #pragma unroll
    for (int d = 1; d < 16; d <<= 1) sum += __shfl_xor(sum, d);
    float r = z - m - logf(sum);
    if (lane < 16) out[(size_t)node * 16 + j] = r;
  }
}

// ---------------------------------------------------------------- launch
extern "C" void kernel_launch(void* const* d_in, const int* in_sizes, int n_in,
                              void* d_out, int out_size, void* d_ws, size_t ws_size,
                              hipStream_t stream) {
  const float* x  = (const float*)d_in[0];
  const void*  ei = d_in[1];
  const float* W1 = (const float*)d_in[2];
  const float* b1 = (const float*)d_in[3];
  const float* W2 = (const float*)d_in[4];
  const float* b2 = (const float*)d_in[5];
  float* out = (float*)d_out;

  const int n = NNODES;
  const int E = in_sizes[1] / 2;

  char* ws = (char*)d_ws;
  size_t off = 0;
  auto alloc = [&](size_t bytes) -> void* {
    void* p = ws + off;
    off = (off + bytes + 255) & ~(size_t)255;
    return p;
  };
  int*   flag     = (int*)  alloc(256);
  int*   cnt16    = (int*)  alloc((size_t)NSUB * n * 4);
  int*   cursor16 = (int*)  alloc((size_t)NSUB * n * 4);
  int*   tot      = (int*)  alloc((size_t)n * 4);
  float* dis      = (float*)alloc((size_t)n * 4);
  int*   rowptr   = (int*)  alloc((size_t)(n + 1) * 4);
  int*   bsum     = (int*)  alloc(4096);
  int*   col      = (int*)  alloc((size_t)E * 4);
  float* g1       = (float*)alloc((size_t)n * 16 * 4);
  float* o1       = (float*)alloc((size_t)n * 16 * 4);
  float* g2       = (float*)alloc((size_t)n * 16 * 4);
  (void)ws_size; (void)n_in; (void)out_size;

  hipMemsetAsync(cnt16, 0, (size_t)NSUB * n * 4, stream);
  k_detect<<<1, 64, 0, stream>>>(ei, flag);
  k_count<<<(E + 255) / 256, 256, 0, stream>>>(ei, flag, cnt16, E);
  k_dis<<<(n + 255) / 256, 256, 0, stream>>>(cnt16, tot, dis, n);

  // GEMM1 only needs dis — run it before the scan/scatter chain.
  k_gemm<512><<<(n + 63) / 64, 64, 0, stream>>>(x, W1, dis, g1, n);

  int nb = (n + 255) / 256;  // 391 <= 512
  k_scan_reduce<<<nb, 256, 0, stream>>>(tot, bsum, n);
  k_scan_partials<<<1, 512, 0, stream>>>(bsum, nb, rowptr, n);
  k_scan_final<<<nb, 256, 0, stream>>>(tot, cnt16, bsum, rowptr, cursor16, n);

  k_scatter<<<(E + 255) / 256, 256, 0, stream>>>(ei, flag, cursor16, col, E);

  k_agg<0><<<(n + 3) / 4, 256, 0, stream>>>(g1, col, rowptr, dis, b1, o1);
  k_gemm<16><<<(n + 63) / 64, 64, 0, stream>>>(o1, W2, dis, g2, n);
  k_agg<1><<<(n + 3) / 4, 256, 0, stream>>>(g2, col, rowptr, dis, b2, out);
}

// Round 5
// 419.782 us; speedup vs baseline: 1.4934x; 1.4934x over previous
//
#include <hip/hip_runtime.h>
#include <hip/hip_bf16.h>
#include <math.h>

#define NNODES 100000
#define NBUCK 8
#define XRANGE 12500                 // NNODES / NBUCK — one bucket's node range (50 KB of ints = fits LDS)
#define NCHUNK 16                    // chunks per bucket for hist/scatter
#define CAP 408192                   // per-bucket edge capacity: E/8 + 8192 (13 sigma), 64-aligned

// ---------------------------------------------------------------- utilities
__device__ __forceinline__ int edge_val(const void* eidx, int is64, size_t i) {
  if (is64) return (int)((const long long*)eidx)[i];
  return ((const int*)eidx)[i];
}

// Detect whether edge_index buffer is int64 or int32.
__global__ void k_detect(const void* eidx, int* flag) {
  int t = threadIdx.x;  // 64 threads, one wave
  int bad = 0;
  const unsigned long long* p = (const unsigned long long*)eidx;
  for (int i = t; i < 1024; i += 64)
    if (p[i] >> 32) bad = 1;
  unsigned long long b = __ballot(bad);
  if (t == 0) flag[0] = (b == 0ULL) ? 1 : 0;
}

// ---------------------------------------------------------------- binning
// Partition edges into 8 dst-range buckets. Per block: ballot-count phase,
// one global atomicAdd per bucket (8/block), then ballot-rank placement.
// Device atomics total: 8 * gridDim = 4096 (vs 3.2M before).
__global__ void k_bin(const void* eidx, const int* __restrict__ flag, int* gcur,
                      int* __restrict__ sArr, unsigned short* __restrict__ dArr, int E) {
  int is64 = flag[0];
  int chunkSz = (E + gridDim.x - 1) / gridDim.x;
  int beg = blockIdx.x * chunkSz;
  int end = min(beg + chunkSz, E);
  int lane = threadIdx.x & 63;
  int wid = threadIdx.x >> 6;
  __shared__ int bbase[NBUCK];
  __shared__ int lcur[NBUCK];
  __shared__ int wcnt[4][NBUCK];
  int nIter = (end > beg) ? ((end - beg + 255) >> 8) : 0;

  // phase A: per-wave ballot counts (lane b<8 accumulates bucket b)
  int cnt_local = 0;
  for (int it = 0; it < nIter; ++it) {
    int e = beg + it * 256 + threadIdx.x;
    int bk = 255;
    if (e < end) {
      int d = edge_val(eidx, is64, (size_t)E + e);
      bk = d / XRANGE;
    }
    #pragma unroll
    for (int b = 0; b < NBUCK; ++b) {
      unsigned long long m = __ballot(bk == b);
      if (lane == b) cnt_local += __popcll(m);
    }
  }
  if (lane < NBUCK) wcnt[wid][lane] = cnt_local;
  __syncthreads();
  if (threadIdx.x < NBUCK) {
    int t = wcnt[0][threadIdx.x] + wcnt[1][threadIdx.x] +
            wcnt[2][threadIdx.x] + wcnt[3][threadIdx.x];
    bbase[threadIdx.x] = atomicAdd(&gcur[threadIdx.x], t);
    lcur[threadIdx.x] = 0;
  }
  __syncthreads();

  // phase C: ballot-rank placement into the block's reservation
  for (int it = 0; it < nIter; ++it) {
    int e = beg + it * 256 + threadIdx.x;
    int bk = 255, s = 0, d = 0;
    if (e < end) {
      s = edge_val(eidx, is64, e);
      d = edge_val(eidx, is64, (size_t)E + e);
      bk = d / XRANGE;
    }
    #pragma unroll
    for (int b = 0; b < NBUCK; ++b) {
      unsigned long long m = __ballot(bk == b);
      int c = __popcll(m);
      if (!c) continue;                      // wave-uniform branch
      int leader = __ffsll((unsigned long long)m) - 1;
      int base = 0;
      if (lane == leader) base = atomicAdd(&lcur[b], c);  // LDS
      base = __shfl(base, leader);
      if (bk == b) {
        int rank = __popcll(m & ((1ULL << lane) - 1));
        int gpos = bbase[b] + base + rank;
        if (gpos < CAP) {                    // safety (statistically unreachable)
          sArr[(size_t)b * CAP + gpos] = s;
          dArr[(size_t)b * CAP + gpos] = (unsigned short)(d - b * XRANGE);
        }
      }
    }
  }
}

// ---------------------------------------------------------------- histogram (replaces k_count)
// block = (bucket b, chunk c); LDS histogram over the bucket's 12500-node range.
__global__ void k_hist(const int* __restrict__ gcur, const unsigned short* __restrict__ dArr,
                       int* __restrict__ cntc) {
  int b = blockIdx.x & (NBUCK - 1);
  int c = blockIdx.x >> 3;
  __shared__ int h[XRANGE];
  for (int i = threadIdx.x; i < XRANGE; i += 256) h[i] = 0;
  __syncthreads();
  int nE = min(gcur[b], CAP);
  int ce = (nE + NCHUNK - 1) / NCHUNK;
  int beg = c * ce, end = min(beg + ce, nE);
  const unsigned short* dp = dArr + (size_t)b * CAP;
  for (int e = beg + threadIdx.x; e < end; e += 256)
    atomicAdd(&h[dp[e]], 1);
  __syncthreads();
  int lo = b * XRANGE;
  for (int i = threadIdx.x; i < XRANGE; i += 256)
    cntc[(size_t)c * NNODES + lo + i] = h[i];
}

// ---------------------------------------------------------------- degree -> dis
__global__ void k_dis(const int* __restrict__ cntc, int* __restrict__ tot,
                      float* __restrict__ dis, int n) {
  int i = blockIdx.x * blockDim.x + threadIdx.x;
  if (i >= n) return;
  int t = 0;
  #pragma unroll
  for (int c = 0; c < NCHUNK; ++c) t += cntc[(size_t)c * NNODES + i];
  tot[i] = t;
  dis[i] = rsqrtf((float)(t + 1));  // +1 = self loop
}

// ---------------------------------------------------------------- scan (3 kernels)
__global__ void k_scan_reduce(const int* __restrict__ tot, int* __restrict__ bsum, int n) {
  int idx = blockIdx.x * 256 + threadIdx.x;
  int v = (idx < n) ? tot[idx] : 0;
  #pragma unroll
  for (int d = 32; d > 0; d >>= 1) v += __shfl_down(v, d);
  __shared__ int ws4[4];
  if ((threadIdx.x & 63) == 0) ws4[threadIdx.x >> 6] = v;
  __syncthreads();
  if (threadIdx.x == 0) bsum[blockIdx.x] = ws4[0] + ws4[1] + ws4[2] + ws4[3];
}

__global__ void k_scan_partials(int* bsum, int nb, int* rowptr, int n) {
  __shared__ int s[512];
  int t = threadIdx.x;  // 512 threads, nb <= 512
  int v = (t < nb) ? bsum[t] : 0;
  s[t] = v;
  __syncthreads();
  for (int d = 1; d < 512; d <<= 1) {
    int u = (t >= d) ? s[t - d] : 0;
    __syncthreads();
    s[t] += u;
    __syncthreads();
  }
  if (t < nb) bsum[t] = (t == 0) ? 0 : s[t - 1];
  if (t == 0) rowptr[n] = s[nb - 1];
}

__global__ void k_scan_final(const int* __restrict__ tot, const int* __restrict__ bsum_ex,
                             int* __restrict__ rowptr, int n) {
  __shared__ int s[256];
  int t = threadIdx.x;
  int idx = blockIdx.x * 256 + t;
  int v = (idx < n) ? tot[idx] : 0;
  s[t] = v;
  __syncthreads();
  for (int d = 1; d < 256; d <<= 1) {
    int u = (t >= d) ? s[t - d] : 0;
    __syncthreads();
    s[t] += u;
    __syncthreads();
  }
  if (idx < n) rowptr[idx] = bsum_ex[blockIdx.x] + s[t] - v;
}

// cross-chunk per-node scan: cntc[c][i] <- rowptr[i] + sum_{c'<c} cnt  (in place)
__global__ void k_scan_chunks(const int* __restrict__ rowptr, int* __restrict__ cntc, int n) {
  int i = blockIdx.x * blockDim.x + threadIdx.x;
  if (i >= n) return;
  int run = rowptr[i];
  #pragma unroll
  for (int c = 0; c < NCHUNK; ++c) {
    size_t idx = (size_t)c * NNODES + i;
    int t = cntc[idx];
    cntc[idx] = run;
    run += t;
  }
}

// ---------------------------------------------------------------- scatter (LDS cursors, no device atomics)
__global__ void k_scatter(const int* __restrict__ gcur, const int* __restrict__ sArr,
                          const unsigned short* __restrict__ dArr,
                          const int* __restrict__ cntc, int* __restrict__ col) {
  int b = blockIdx.x & (NBUCK - 1);   // bucket == XCD (round-robin dispatch heuristic)
  int c = blockIdx.x >> 3;
  __shared__ int cur[XRANGE];
  int lo = b * XRANGE;
  for (int i = threadIdx.x; i < XRANGE; i += 256)
    cur[i] = cntc[(size_t)c * NNODES + lo + i];
  __syncthreads();
  int nE = min(gcur[b], CAP);
  int ce = (nE + NCHUNK - 1) / NCHUNK;
  int beg = c * ce, end = min(beg + ce, nE);
  const int* sp = sArr + (size_t)b * CAP;
  const unsigned short* dp = dArr + (size_t)b * CAP;
  for (int e = beg + threadIdx.x; e < end; e += 256) {
    int d = dp[e];
    int pos = atomicAdd(&cur[d], 1);  // LDS atomic
    col[pos] = sp[e];
  }
}

// ---------------------------------------------------------------- GEMM (N=16)
template <int K>
__global__ void k_gemm(const float* __restrict__ x, const float* __restrict__ W,
                       const float* __restrict__ dis, float* __restrict__ out, int nrows) {
  int row = blockIdx.x * blockDim.x + threadIdx.x;
  if (row >= nrows) return;
  const float4* xr = (const float4*)(x + (size_t)row * K);
  float acc[16];
  #pragma unroll
  for (int j = 0; j < 16; ++j) acc[j] = 0.f;
  #pragma unroll 2
  for (int k4 = 0; k4 < K / 4; ++k4) {
    float4 xv = xr[k4];
    const float* xs = (const float*)&xv;
    #pragma unroll
    for (int kk = 0; kk < 4; ++kk) {
      #pragma unroll
      for (int j = 0; j < 16; ++j)
        acc[j] = fmaf(xs[kk], W[(size_t)(k4 * 4 + kk) * 16 + j], acc[j]);
    }
  }
  float dd = dis[row];
  float4* o = (float4*)(out + (size_t)row * 16);
  #pragma unroll
  for (int q = 0; q < 4; ++q)
    o[q] = make_float4(acc[q * 4] * dd, acc[q * 4 + 1] * dd,
                       acc[q * 4 + 2] * dd, acc[q * 4 + 3] * dd);
}

// ---------------------------------------------------------------- aggregation
template <int MODE>
__global__ void k_agg(const float* __restrict__ g, const int* __restrict__ col,
                      const int* __restrict__ rowptr, const float* __restrict__ dis,
                      const float* __restrict__ bias, float* __restrict__ out) {
  int wid = threadIdx.x >> 6;
  int node = blockIdx.x * (blockDim.x >> 6) + wid;
  if (node >= NNODES) return;
  int lane = threadIdx.x & 63;
  int slot = lane >> 4;
  int j = lane & 15;
  int beg = rowptr[node], end = rowptr[node + 1];
  float acc = 0.f;
  for (int e = beg + slot; e < end; e += 4) {
    int s = col[e];
    acc += g[(size_t)s * 16 + j];
  }
  acc += __shfl_xor(acc, 16);
  acc += __shfl_xor(acc, 32);
  float z = dis[node] * (acc + g[(size_t)node * 16 + j]) + bias[j];
  if (MODE == 0) {
    z = fmaxf(z, 0.f);
    if (lane < 16) out[(size_t)node * 16 + j] = z;
  } else {
    float m = z;
    #pragma unroll
    for (int d = 1; d < 16; d <<= 1) m = fmaxf(m, __shfl_xor(m, d));
    float ex = expf(z - m);
    float sum = ex;
    #pragma unroll
    for (int d = 1; d < 16; d <<= 1) sum += __shfl_xor(sum, d);
    float r = z - m - logf(sum);
    if (lane < 16) out[(size_t)node * 16 + j] = r;
  }
}

// ---------------------------------------------------------------- launch
extern "C" void kernel_launch(void* const* d_in, const int* in_sizes, int n_in,
                              void* d_out, int out_size, void* d_ws, size_t ws_size,
                              hipStream_t stream) {
  const float* x  = (const float*)d_in[0];
  const void*  ei = d_in[1];
  const float* W1 = (const float*)d_in[2];
  const float* b1 = (const float*)d_in[3];
  const float* W2 = (const float*)d_in[4];
  const float* b2 = (const float*)d_in[5];
  float* out = (float*)d_out;

  const int n = NNODES;
  const int E = in_sizes[1] / 2;

  char* ws = (char*)d_ws;
  size_t off = 0;
  auto alloc = [&](size_t bytes) -> void* {
    void* p = ws + off;
    off = (off + bytes + 255) & ~(size_t)255;
    return p;
  };
  int*            flag   = (int*)            alloc(256);
  int*            gcur   = (int*)            alloc(256);
  int*            sArr   = (int*)            alloc((size_t)NBUCK * CAP * 4);  // 13.1 MB
  unsigned short* dArr   = (unsigned short*) alloc((size_t)NBUCK * CAP * 2);  // 6.5 MB
  int*            cntc   = (int*)            alloc((size_t)NCHUNK * n * 4);   // 6.4 MB
  int*            tot    = (int*)            alloc((size_t)n * 4);
  float*          dis    = (float*)          alloc((size_t)n * 4);
  int*            rowptr = (int*)            alloc((size_t)(n + 1) * 4);
  int*            bsum   = (int*)            alloc(4096);
  int*            col    = (int*)            alloc((size_t)E * 4);            // 12.8 MB
  float*          g1     = (float*)          alloc((size_t)n * 16 * 4);       // 6.4 MB
  // overlays: sArr/dArr are dead after k_scatter; agg0/gemm2 run later.
  float*          o1     = (float*)dArr;   // 6.4 MB fits in dArr's 6.53 MB
  float*          g2     = (float*)sArr;   // 6.4 MB fits in sArr's 13.1 MB
  (void)ws_size; (void)n_in; (void)out_size;

  hipMemsetAsync(gcur, 0, 256, stream);
  k_detect<<<1, 64, 0, stream>>>(ei, flag);
  k_bin<<<512, 256, 0, stream>>>(ei, flag, gcur, sArr, dArr, E);
  k_hist<<<NBUCK * NCHUNK, 256, 0, stream>>>(gcur, dArr, cntc);
  k_dis<<<(n + 255) / 256, 256, 0, stream>>>(cntc, tot, dis, n);

  // GEMM1 only needs dis.
  k_gemm<512><<<(n + 63) / 64, 64, 0, stream>>>(x, W1, dis, g1, n);

  int nb = (n + 255) / 256;  // 391 <= 512
  k_scan_reduce<<<nb, 256, 0, stream>>>(tot, bsum, n);
  k_scan_partials<<<1, 512, 0, stream>>>(bsum, nb, rowptr, n);
  k_scan_final<<<nb, 256, 0, stream>>>(tot, bsum, rowptr, n);
  k_scan_chunks<<<nb, 256, 0, stream>>>(rowptr, cntc, n);

  k_scatter<<<NBUCK * NCHUNK, 256, 0, stream>>>(gcur, sArr, dArr, cntc, col);

  k_agg<0><<<(n + 3) / 4, 256, 0, stream>>>(g1, col, rowptr, dis, b1, o1);
  k_gemm<16><<<(n + 63) / 64, 64, 0, stream>>>(o1, W2, dis, g2, n);
  k_agg<1><<<(n + 3) / 4, 256, 0, stream>>>(g2, col, rowptr, dis, b2, out);
}

// Round 6
// 340.296 us; speedup vs baseline: 1.8422x; 1.2336x over previous
//
#include <hip/hip_runtime.h>
#include <hip/hip_bf16.h>
#include <math.h>

#define NNODES 100000
#define NBUCK 8
#define XRANGE 12500                 // NNODES / NBUCK — one bucket's node range (50 KB of ints = fits LDS)
#define NCHUNK 16                    // chunks per bucket for hist/scatter
#define CAP 408192                   // per-bucket edge capacity: E/8 + 8192 (13 sigma), 64-aligned

// ---------------------------------------------------------------- utilities
__device__ __forceinline__ int edge_val(const void* eidx, int is64, size_t i) {
  if (is64) return (int)((const long long*)eidx)[i];
  return ((const int*)eidx)[i];
}

// zero gcur without a runtime fillBuffer node (the 256-B hipMemsetAsync's
// rocclr fill dispatch measured 116 us/replay in-graph — kernel instead)
__global__ void k_zero(int* gcur) {
  if (threadIdx.x < NBUCK) gcur[threadIdx.x] = 0;
}

// Detect whether edge_index buffer is int64 or int32.
__global__ void k_detect(const void* eidx, int* flag) {
  int t = threadIdx.x;  // 64 threads, one wave
  int bad = 0;
  const unsigned long long* p = (const unsigned long long*)eidx;
  for (int i = t; i < 1024; i += 64)
    if (p[i] >> 32) bad = 1;
  unsigned long long b = __ballot(bad);
  if (t == 0) flag[0] = (b == 0ULL) ? 1 : 0;
}

// ---------------------------------------------------------------- binning
// Partition edges into 8 dst-range buckets. Per block: ballot-count phase,
// one global atomicAdd per bucket (8/block), then ballot-rank placement.
__global__ void k_bin(const void* eidx, const int* __restrict__ flag, int* gcur,
                      int* __restrict__ sArr, unsigned short* __restrict__ dArr, int E) {
  int is64 = flag[0];
  int chunkSz = (E + gridDim.x - 1) / gridDim.x;
  int beg = blockIdx.x * chunkSz;
  int end = min(beg + chunkSz, E);
  int lane = threadIdx.x & 63;
  int wid = threadIdx.x >> 6;
  __shared__ int bbase[NBUCK];
  __shared__ int lcur[NBUCK];
  __shared__ int wcnt[4][NBUCK];
  int nIter = (end > beg) ? ((end - beg + 255) >> 8) : 0;

  // phase A: per-wave ballot counts (lane b<8 accumulates bucket b)
  int cnt_local = 0;
  for (int it = 0; it < nIter; ++it) {
    int e = beg + it * 256 + threadIdx.x;
    int bk = 255;
    if (e < end) {
      int d = edge_val(eidx, is64, (size_t)E + e);
      bk = d / XRANGE;
    }
    #pragma unroll
    for (int b = 0; b < NBUCK; ++b) {
      unsigned long long m = __ballot(bk == b);
      if (lane == b) cnt_local += __popcll(m);
    }
  }
  if (lane < NBUCK) wcnt[wid][lane] = cnt_local;
  __syncthreads();
  if (threadIdx.x < NBUCK) {
    int t = wcnt[0][threadIdx.x] + wcnt[1][threadIdx.x] +
            wcnt[2][threadIdx.x] + wcnt[3][threadIdx.x];
    bbase[threadIdx.x] = atomicAdd(&gcur[threadIdx.x], t);
    lcur[threadIdx.x] = 0;
  }
  __syncthreads();

  // phase C: ballot-rank placement into the block's reservation
  for (int it = 0; it < nIter; ++it) {
    int e = beg + it * 256 + threadIdx.x;
    int bk = 255, s = 0, d = 0;
    if (e < end) {
      s = edge_val(eidx, is64, e);
      d = edge_val(eidx, is64, (size_t)E + e);
      bk = d / XRANGE;
    }
    #pragma unroll
    for (int b = 0; b < NBUCK; ++b) {
      unsigned long long m = __ballot(bk == b);
      int c = __popcll(m);
      if (!c) continue;                      // wave-uniform branch
      int leader = __ffsll((unsigned long long)m) - 1;
      int base = 0;
      if (lane == leader) base = atomicAdd(&lcur[b], c);  // LDS
      base = __shfl(base, leader);
      if (bk == b) {
        int rank = __popcll(m & ((1ULL << lane) - 1));
        int gpos = bbase[b] + base + rank;
        if (gpos < CAP) {                    // safety (statistically unreachable)
          sArr[(size_t)b * CAP + gpos] = s;
          dArr[(size_t)b * CAP + gpos] = (unsigned short)(d - b * XRANGE);
        }
      }
    }
  }
}

// ---------------------------------------------------------------- histogram (replaces k_count)
__global__ void k_hist(const int* __restrict__ gcur, const unsigned short* __restrict__ dArr,
                       int* __restrict__ cntc) {
  int b = blockIdx.x & (NBUCK - 1);
  int c = blockIdx.x >> 3;
  __shared__ int h[XRANGE];
  for (int i = threadIdx.x; i < XRANGE; i += 256) h[i] = 0;
  __syncthreads();
  int nE = min(gcur[b], CAP);
  int ce = (nE + NCHUNK - 1) / NCHUNK;
  int beg = c * ce, end = min(beg + ce, nE);
  const unsigned short* dp = dArr + (size_t)b * CAP;
  for (int e = beg + threadIdx.x; e < end; e += 256)
    atomicAdd(&h[dp[e]], 1);
  __syncthreads();
  int lo = b * XRANGE;
  for (int i = threadIdx.x; i < XRANGE; i += 256)
    cntc[(size_t)c * NNODES + lo + i] = h[i];
}

// ---------------------------------------------------------------- degree -> dis
__global__ void k_dis(const int* __restrict__ cntc, int* __restrict__ tot,
                      float* __restrict__ dis, int n) {
  int i = blockIdx.x * blockDim.x + threadIdx.x;
  if (i >= n) return;
  int t = 0;
  #pragma unroll
  for (int c = 0; c < NCHUNK; ++c) t += cntc[(size_t)c * NNODES + i];
  tot[i] = t;
  dis[i] = rsqrtf((float)(t + 1));  // +1 = self loop
}

// ---------------------------------------------------------------- scan (3 kernels)
__global__ void k_scan_reduce(const int* __restrict__ tot, int* __restrict__ bsum, int n) {
  int idx = blockIdx.x * 256 + threadIdx.x;
  int v = (idx < n) ? tot[idx] : 0;
  #pragma unroll
  for (int d = 32; d > 0; d >>= 1) v += __shfl_down(v, d);
  __shared__ int ws4[4];
  if ((threadIdx.x & 63) == 0) ws4[threadIdx.x >> 6] = v;
  __syncthreads();
  if (threadIdx.x == 0) bsum[blockIdx.x] = ws4[0] + ws4[1] + ws4[2] + ws4[3];
}

__global__ void k_scan_partials(int* bsum, int nb, int* rowptr, int n) {
  __shared__ int s[512];
  int t = threadIdx.x;  // 512 threads, nb <= 512
  int v = (t < nb) ? bsum[t] : 0;
  s[t] = v;
  __syncthreads();
  for (int d = 1; d < 512; d <<= 1) {
    int u = (t >= d) ? s[t - d] : 0;
    __syncthreads();
    s[t] += u;
    __syncthreads();
  }
  if (t < nb) bsum[t] = (t == 0) ? 0 : s[t - 1];
  if (t == 0) rowptr[n] = s[nb - 1];
}

__global__ void k_scan_final(const int* __restrict__ tot, const int* __restrict__ bsum_ex,
                             int* __restrict__ rowptr, int n) {
  __shared__ int s[256];
  int t = threadIdx.x;
  int idx = blockIdx.x * 256 + t;
  int v = (idx < n) ? tot[idx] : 0;
  s[t] = v;
  __syncthreads();
  for (int d = 1; d < 256; d <<= 1) {
    int u = (t >= d) ? s[t - d] : 0;
    __syncthreads();
    s[t] += u;
    __syncthreads();
  }
  if (idx < n) rowptr[idx] = bsum_ex[blockIdx.x] + s[t] - v;
}

// cross-chunk per-node scan: cntc[c][i] <- rowptr[i] + sum_{c'<c} cnt  (in place)
__global__ void k_scan_chunks(const int* __restrict__ rowptr, int* __restrict__ cntc, int n) {
  int i = blockIdx.x * blockDim.x + threadIdx.x;
  if (i >= n) return;
  int run = rowptr[i];
  #pragma unroll
  for (int c = 0; c < NCHUNK; ++c) {
    size_t idx = (size_t)c * NNODES + i;
    int t = cntc[idx];
    cntc[idx] = run;
    run += t;
  }
}

// ---------------------------------------------------------------- scatter (LDS cursors, no device atomics)
__global__ void k_scatter(const int* __restrict__ gcur, const int* __restrict__ sArr,
                          const unsigned short* __restrict__ dArr,
                          const int* __restrict__ cntc, int* __restrict__ col) {
  int b = blockIdx.x & (NBUCK - 1);
  int c = blockIdx.x >> 3;
  __shared__ int cur[XRANGE];
  int lo = b * XRANGE;
  for (int i = threadIdx.x; i < XRANGE; i += 256)
    cur[i] = cntc[(size_t)c * NNODES + lo + i];
  __syncthreads();
  int nE = min(gcur[b], CAP);
  int ce = (nE + NCHUNK - 1) / NCHUNK;
  int beg = c * ce, end = min(beg + ce, nE);
  const int* sp = sArr + (size_t)b * CAP;
  const unsigned short* dp = dArr + (size_t)b * CAP;
  for (int e = beg + threadIdx.x; e < end; e += 256) {
    int d = dp[e];
    int pos = atomicAdd(&cur[d], 1);  // LDS atomic
    col[pos] = sp[e];
  }
}

// ---------------------------------------------------------------- GEMM (N=16)
template <int K>
__global__ void k_gemm(const float* __restrict__ x, const float* __restrict__ W,
                       const float* __restrict__ dis, float* __restrict__ out, int nrows) {
  int row = blockIdx.x * blockDim.x + threadIdx.x;
  if (row >= nrows) return;
  const float4* xr = (const float4*)(x + (size_t)row * K);
  float acc[16];
  #pragma unroll
  for (int j = 0; j < 16; ++j) acc[j] = 0.f;
  #pragma unroll 2
  for (int k4 = 0; k4 < K / 4; ++k4) {
    float4 xv = xr[k4];
    const float* xs = (const float*)&xv;
    #pragma unroll
    for (int kk = 0; kk < 4; ++kk) {
      #pragma unroll
      for (int j = 0; j < 16; ++j)
        acc[j] = fmaf(xs[kk], W[(size_t)(k4 * 4 + kk) * 16 + j], acc[j]);
    }
  }
  float dd = dis[row];
  float4* o = (float4*)(out + (size_t)row * 16);
  #pragma unroll
  for (int q = 0; q < 4; ++q)
    o[q] = make_float4(acc[q * 4] * dd, acc[q * 4 + 1] * dd,
                       acc[q * 4 + 2] * dd, acc[q * 4 + 3] * dd);
}

// ---------------------------------------------------------------- aggregation
// wave per node; lane = (edge_slot 0..15, q 0..3) — float4 per lane.
// 16 edges in flight per iteration (16 cache lines of MLP per wave load).
template <int MODE>
__global__ void k_agg(const float* __restrict__ g, const int* __restrict__ col,
                      const int* __restrict__ rowptr, const float* __restrict__ dis,
                      const float* __restrict__ bias, float* __restrict__ out) {
  int wid = threadIdx.x >> 6;
  int node = blockIdx.x * (blockDim.x >> 6) + wid;
  if (node >= NNODES) return;
  int lane = threadIdx.x & 63;
  int slot = lane >> 2;  // 0..15 edge slot
  int q = lane & 3;      // float4 quadrant of the 16 features
  int beg = rowptr[node], end = rowptr[node + 1];
  const float4* g4 = (const float4*)g;
  float4 acc = make_float4(0.f, 0.f, 0.f, 0.f);
  for (int e = beg + slot; e < end; e += 16) {
    int s = col[e];
    float4 v = g4[(size_t)s * 4 + q];
    acc.x += v.x; acc.y += v.y; acc.z += v.z; acc.w += v.w;
  }
  // butterfly over slot bits (2..5): every lane ends with the full per-q sum
  #pragma unroll
  for (int d = 4; d < 64; d <<= 1) {
    acc.x += __shfl_xor(acc.x, d);
    acc.y += __shfl_xor(acc.y, d);
    acc.z += __shfl_xor(acc.z, d);
    acc.w += __shfl_xor(acc.w, d);
  }
  float4 gs = g4[(size_t)node * 4 + q];
  float dd = dis[node];
  float4 bb = ((const float4*)bias)[q];
  float4 z;
  z.x = dd * (acc.x + gs.x) + bb.x;
  z.y = dd * (acc.y + gs.y) + bb.y;
  z.z = dd * (acc.z + gs.z) + bb.z;
  z.w = dd * (acc.w + gs.w) + bb.w;
  if (MODE == 0) {
    z.x = fmaxf(z.x, 0.f); z.y = fmaxf(z.y, 0.f);
    z.z = fmaxf(z.z, 0.f); z.w = fmaxf(z.w, 0.f);
    if (lane < 4) ((float4*)out)[(size_t)node * 4 + q] = z;
  } else {
    float m = fmaxf(fmaxf(z.x, z.y), fmaxf(z.z, z.w));
    m = fmaxf(m, __shfl_xor(m, 1));
    m = fmaxf(m, __shfl_xor(m, 2));
    float se = expf(z.x - m) + expf(z.y - m) + expf(z.z - m) + expf(z.w - m);
    se += __shfl_xor(se, 1);
    se += __shfl_xor(se, 2);
    float lg = m + logf(se);
    z.x -= lg; z.y -= lg; z.z -= lg; z.w -= lg;
    if (lane < 4) ((float4*)out)[(size_t)node * 4 + q] = z;
  }
}

// ---------------------------------------------------------------- launch
extern "C" void kernel_launch(void* const* d_in, const int* in_sizes, int n_in,
                              void* d_out, int out_size, void* d_ws, size_t ws_size,
                              hipStream_t stream) {
  const float* x  = (const float*)d_in[0];
  const void*  ei = d_in[1];
  const float* W1 = (const float*)d_in[2];
  const float* b1 = (const float*)d_in[3];
  const float* W2 = (const float*)d_in[4];
  const float* b2 = (const float*)d_in[5];
  float* out = (float*)d_out;

  const int n = NNODES;
  const int E = in_sizes[1] / 2;

  char* ws = (char*)d_ws;
  size_t off = 0;
  auto alloc = [&](size_t bytes) -> void* {
    void* p = ws + off;
    off = (off + bytes + 255) & ~(size_t)255;
    return p;
  };
  int*            flag   = (int*)            alloc(256);
  int*            gcur   = (int*)            alloc(256);
  int*            sArr   = (int*)            alloc((size_t)NBUCK * CAP * 4);  // 13.1 MB
  unsigned short* dArr   = (unsigned short*) alloc((size_t)NBUCK * CAP * 2);  // 6.5 MB
  int*            cntc   = (int*)            alloc((size_t)NCHUNK * n * 4);   // 6.4 MB
  int*            tot    = (int*)            alloc((size_t)n * 4);
  float*          dis    = (float*)          alloc((size_t)n * 4);
  int*            rowptr = (int*)            alloc((size_t)(n + 1) * 4);
  int*            bsum   = (int*)            alloc(4096);
  int*            col    = (int*)            alloc((size_t)E * 4);            // 12.8 MB
  float*          g1     = (float*)          alloc((size_t)n * 16 * 4);       // 6.4 MB
  // overlays: sArr/dArr are dead after k_scatter; agg0/gemm2 run later.
  float*          o1     = (float*)dArr;   // 6.4 MB fits in dArr's 6.53 MB
  float*          g2     = (float*)sArr;   // 6.4 MB fits in sArr's 13.1 MB
  (void)ws_size; (void)n_in; (void)out_size;

  k_zero<<<1, 64, 0, stream>>>(gcur);
  k_detect<<<1, 64, 0, stream>>>(ei, flag);
  k_bin<<<512, 256, 0, stream>>>(ei, flag, gcur, sArr, dArr, E);
  k_hist<<<NBUCK * NCHUNK, 256, 0, stream>>>(gcur, dArr, cntc);
  k_dis<<<(n + 255) / 256, 256, 0, stream>>>(cntc, tot, dis, n);

  // GEMM1 only needs dis.
  k_gemm<512><<<(n + 63) / 64, 64, 0, stream>>>(x, W1, dis, g1, n);

  int nb = (n + 255) / 256;  // 391 <= 512
  k_scan_reduce<<<nb, 256, 0, stream>>>(tot, bsum, n);
  k_scan_partials<<<1, 512, 0, stream>>>(bsum, nb, rowptr, n);
  k_scan_final<<<nb, 256, 0, stream>>>(tot, bsum, rowptr, n);
  k_scan_chunks<<<nb, 256, 0, stream>>>(rowptr, cntc, n);

  k_scatter<<<NBUCK * NCHUNK, 256, 0, stream>>>(gcur, sArr, dArr, cntc, col);

  k_agg<0><<<(n + 3) / 4, 256, 0, stream>>>(g1, col, rowptr, dis, b1, o1);
  k_gemm<16><<<(n + 63) / 64, 64, 0, stream>>>(o1, W2, dis, g2, n);
  k_agg<1><<<(n + 3) / 4, 256, 0, stream>>>(g2, col, rowptr, dis, b2, out);
}